// Round 1
// baseline (240.909 us; speedup 1.0000x reference)
//
#include <hip/hip_runtime.h>

// GraphAttentionWithTypedEdges — MI355X bf16 MFMA implementation.
// B=2, T=2048, D=1024, H=16, hd=64, E=16384.
//
// ws layout (bytes):
//   [0,8M)    Wt3: Wq^T,Wk^T,Wv^T,Wo^T bf16, each [1024][1024] (first three
//             contiguous => one [3072][1024] matrix for the fused QKV GEMM)
//   [8M,16M)  Q  bf16 [B,H,T,64] (pre-scaled by 0.125)
//   [16M,24M) K  bf16 [B,H,T,64]
//   [24M,32M) Vt bf16 [B,H,64,T]
//   [32M,40M) attn out bf16 [B,T,H*64]
//   [40M,56M) Bias fp32 [2048][2048]
//   [56M,+16) bias3 fp32[3]
// d_out first 8 MB doubles as x_bf16 scratch (dead before final GEMM writes).

typedef __attribute__((ext_vector_type(4))) float f32x4;
typedef __bf16 bf16x8 __attribute__((ext_vector_type(8)));

#define DEV static __device__ __forceinline__

DEV ushort f2bf(float f) {
  unsigned u = __float_as_uint(f);
  unsigned r = u + 0x7fffu + ((u >> 16) & 1u);
  return (ushort)(r >> 16);
}

DEV void gl_lds16(const void* g, void* l) {
  __builtin_amdgcn_global_load_lds(
      (const __attribute__((address_space(1))) void*)g,
      (__attribute__((address_space(3))) void*)l, 16, 0, 0);
}

// ---------------- conversions ----------------
__global__ __launch_bounds__(256) void cvtx_kernel(const float* __restrict__ X,
                                                   ushort* __restrict__ Y) {
  int i = blockIdx.x * 256 + threadIdx.x;  // grid sized exactly
  float4 v = ((const float4*)X)[i];
  ushort4 o;
  o.x = f2bf(v.x); o.y = f2bf(v.y); o.z = f2bf(v.z); o.w = f2bf(v.w);
  ((ushort4*)Y)[i] = o;
}

// W [1024][1024] fp32 -> Wt [1024][1024] bf16 with Wt[n][k] = W[k][n]
__global__ __launch_bounds__(256) void tcvt_kernel(const float* __restrict__ W,
                                                   ushort* __restrict__ Wt) {
  __shared__ float tile[32][33];
  int bx = blockIdx.x * 32, by = blockIdx.y * 32;
  int tx = threadIdx.x & 31, ty = threadIdx.x >> 5;
#pragma unroll
  for (int i = 0; i < 32; i += 8)
    tile[ty + i][tx] = W[(size_t)(by + ty + i) * 1024 + bx + tx];
  __syncthreads();
#pragma unroll
  for (int i = 0; i < 32; i += 8)
    Wt[(size_t)(bx + ty + i) * 1024 + by + tx] = f2bf(tile[tx][ty + i]);
}

// ---------------- edge bias ----------------
__global__ __launch_bounds__(256) void bias3_kernel(const float* __restrict__ emb,
                                                    const float* __restrict__ tw,
                                                    float* __restrict__ b3) {
  __shared__ float red[256];
  const int t = blockIdx.x;
  float p = 0.f;
  for (int d = threadIdx.x; d < 1024; d += 256) p += emb[t * 1024 + d] * tw[d];
  red[threadIdx.x] = p;
  __syncthreads();
  for (int s = 128; s > 0; s >>= 1) {
    if (threadIdx.x < s) red[threadIdx.x] += red[threadIdx.x + s];
    __syncthreads();
  }
  if (threadIdx.x == 0) b3[t] = red[0];
}

__global__ __launch_bounds__(256) void scatter_kernel(
    const int* __restrict__ src, const int* __restrict__ dst,
    const int* __restrict__ typ, const float* __restrict__ b3,
    float* __restrict__ Bias, int E) {
  int e = blockIdx.x * 256 + threadIdx.x;
  if (e < E) atomicAdd(&Bias[(size_t)src[e] * 2048 + dst[e]], b3[typ[e]]);
}

// ---------------- GEMMs ----------------
// Both GEMMs: A [4096][1024] bf16 row-major, Bt [N][1024] bf16 (B transposed).
// 128x128 tile, BK=64, 256 threads (4 waves, 2x2 of 64x64).
// LDS "chunked" layout: [kk(2)][blk16(8)][row16(16)][g(4)] x 16B so that every
// wave ds_read_b128 (one (kk,blk) block) covers a contiguous 1 KiB region
// (conflict-free) while global_load_lds staging stays linear.

// Fused QKV: Bt3 = [3072][1024]; piece 0->Q (scaled 0.125), 1->K, 2->V^T.
__global__ __launch_bounds__(256) void gemm_qkv_kernel(
    const ushort* __restrict__ A, const ushort* __restrict__ Bt3,
    const float* __restrict__ bq, const float* __restrict__ bk,
    const float* __restrict__ bv, ushort* __restrict__ Qo,
    ushort* __restrict__ Ko, ushort* __restrict__ Vto) {
  __shared__ alignas(16) char Als[16384];
  __shared__ alignas(16) char Bls[16384];
  const int tid = threadIdx.x, w = tid >> 6, l = tid & 63;
  const int m0 = blockIdx.y * 128, n0 = blockIdx.x * 128;
  const int sr = l >> 2, sg = l & 3;
  const int c = l & 15, gg = l >> 4;
  const int wr = (w >> 1) * 64, wc = (w & 1) * 64;

  f32x4 acc[4][4];
  const f32x4 zf = {0.f, 0.f, 0.f, 0.f};
#pragma unroll
  for (int a2 = 0; a2 < 4; ++a2)
#pragma unroll
    for (int b2 = 0; b2 < 4; ++b2) acc[a2][b2] = zf;

  for (int k0 = 0; k0 < 1024; k0 += 64) {
#pragma unroll
    for (int j = 0; j < 4; ++j) {
      const int idx = w * 4 + j, kk = idx >> 3, mb = idx & 7;
      gl_lds16(A + (size_t)(m0 + mb * 16 + sr) * 1024 + k0 + kk * 32 + sg * 8,
               &Als[idx * 1024]);
      gl_lds16(Bt3 + (size_t)(n0 + mb * 16 + sr) * 1024 + k0 + kk * 32 + sg * 8,
               &Bls[idx * 1024]);
    }
    __syncthreads();
#pragma unroll
    for (int kk = 0; kk < 2; ++kk) {
      bf16x8 af[4], bfr[4];
#pragma unroll
      for (int f = 0; f < 4; ++f) {
        af[f]  = *(const bf16x8*)&Als[(kk * 8 + (wr >> 4) + f) * 1024 + c * 64 + gg * 16];
        bfr[f] = *(const bf16x8*)&Bls[(kk * 8 + (wc >> 4) + f) * 1024 + c * 64 + gg * 16];
      }
#pragma unroll
      for (int mf = 0; mf < 4; ++mf)
#pragma unroll
        for (int nf = 0; nf < 4; ++nf)
          acc[mf][nf] = __builtin_amdgcn_mfma_f32_16x16x32_bf16(
              af[mf], bfr[nf], acc[mf][nf], 0, 0, 0);
    }
    __syncthreads();
  }

  const int which = n0 >> 10;  // uniform per block (128 | 1024)
  const float scale = (which == 0) ? 0.125f : 1.0f;
  const float* bias = (which == 0) ? bq : (which == 1) ? bk : bv;
  ushort* outp = (which == 0) ? Qo : (which == 1) ? Ko : Vto;
#pragma unroll
  for (int mf = 0; mf < 4; ++mf) {
#pragma unroll
    for (int nf = 0; nf < 4; ++nf) {
      const int coln = (n0 & 1023) + wc + nf * 16 + c;  // 0..1023
      const float bvv = bias[coln];
      const int h = coln >> 6, d = coln & 63;
#pragma unroll
      for (int i = 0; i < 4; ++i) {
        const int row = m0 + wr + mf * 16 + gg * 4 + i;
        const int b = row >> 11, t = row & 2047;
        const float v = (acc[mf][nf][i] + bvv) * scale;
        if (which < 2)
          outp[((size_t)(b * 16 + h) * 2048 + t) * 64 + d] = f2bf(v);
        else
          outp[((size_t)(b * 16 + h) * 64 + d) * 2048 + t] = f2bf(v);
      }
    }
  }
}

// Output projection: C fp32 [4096][1024] = A(bf16) * Wo + bo
__global__ __launch_bounds__(256) void gemm_out_kernel(
    const ushort* __restrict__ A, const ushort* __restrict__ Bt,
    const float* __restrict__ bias, float* __restrict__ outp) {
  __shared__ alignas(16) char Als[16384];
  __shared__ alignas(16) char Bls[16384];
  const int tid = threadIdx.x, w = tid >> 6, l = tid & 63;
  const int m0 = blockIdx.y * 128, n0 = blockIdx.x * 128;
  const int sr = l >> 2, sg = l & 3;
  const int c = l & 15, gg = l >> 4;
  const int wr = (w >> 1) * 64, wc = (w & 1) * 64;

  f32x4 acc[4][4];
  const f32x4 zf = {0.f, 0.f, 0.f, 0.f};
#pragma unroll
  for (int a2 = 0; a2 < 4; ++a2)
#pragma unroll
    for (int b2 = 0; b2 < 4; ++b2) acc[a2][b2] = zf;

  for (int k0 = 0; k0 < 1024; k0 += 64) {
#pragma unroll
    for (int j = 0; j < 4; ++j) {
      const int idx = w * 4 + j, kk = idx >> 3, mb = idx & 7;
      gl_lds16(A + (size_t)(m0 + mb * 16 + sr) * 1024 + k0 + kk * 32 + sg * 8,
               &Als[idx * 1024]);
      gl_lds16(Bt + (size_t)(n0 + mb * 16 + sr) * 1024 + k0 + kk * 32 + sg * 8,
               &Bls[idx * 1024]);
    }
    __syncthreads();
#pragma unroll
    for (int kk = 0; kk < 2; ++kk) {
      bf16x8 af[4], bfr[4];
#pragma unroll
      for (int f = 0; f < 4; ++f) {
        af[f]  = *(const bf16x8*)&Als[(kk * 8 + (wr >> 4) + f) * 1024 + c * 64 + gg * 16];
        bfr[f] = *(const bf16x8*)&Bls[(kk * 8 + (wc >> 4) + f) * 1024 + c * 64 + gg * 16];
      }
#pragma unroll
      for (int mf = 0; mf < 4; ++mf)
#pragma unroll
        for (int nf = 0; nf < 4; ++nf)
          acc[mf][nf] = __builtin_amdgcn_mfma_f32_16x16x32_bf16(
              af[mf], bfr[nf], acc[mf][nf], 0, 0, 0);
    }
    __syncthreads();
  }

#pragma unroll
  for (int mf = 0; mf < 4; ++mf) {
#pragma unroll
    for (int nf = 0; nf < 4; ++nf) {
      const int col = n0 + wc + nf * 16 + c;
      const float bvv = bias[col];
#pragma unroll
      for (int i = 0; i < 4; ++i) {
        const int row = m0 + wr + mf * 16 + gg * 4 + i;
        outp[(size_t)row * 1024 + col] = acc[mf][nf][i] + bvv;
      }
    }
  }
}

// ---------------- flash attention ----------------
// grid (16 qtiles, 32 b*h), 256 threads = 4 waves; wave w owns 32 q rows.
__global__ __launch_bounds__(256) void attn_kernel(
    const ushort* __restrict__ Q, const ushort* __restrict__ K,
    const ushort* __restrict__ Vt, const float* __restrict__ Bias,
    ushort* __restrict__ Out) {
  __shared__ alignas(16) char Qs[16384];
  __shared__ alignas(16) char Ks[8192];
  __shared__ alignas(16) char Vs[8192];
  __shared__ alignas(16) char Ps[16384];
  const int tid = threadIdx.x, w = tid >> 6, l = tid & 63;
  const int bh = blockIdx.y, q0 = blockIdx.x * 128;
  const int bI = bh >> 4, h = bh & 15;
  const ushort* Qb = Q + (size_t)bh * 2048 * 64 + (size_t)q0 * 64;
  const ushort* Kb = K + (size_t)bh * 2048 * 64;
  const ushort* Vb = Vt + (size_t)bh * 64 * 2048;
  const int sr = l >> 2, sg = l & 3;
  const int c = l & 15, gg = l >> 4;
  const int qb0 = w * 2;
  const f32x4 zf = {0.f, 0.f, 0.f, 0.f};

#pragma unroll
  for (int j = 0; j < 4; ++j) {
    const int idx = w * 4 + j, kk = idx >> 3, mb = idx & 7;
    gl_lds16(Qb + (size_t)(mb * 16 + sr) * 64 + kk * 32 + sg * 8, &Qs[idx * 1024]);
  }

  float mrow[2][4], lrow[2][4];
  f32x4 acco[2][4];
#pragma unroll
  for (int qi = 0; qi < 2; ++qi)
#pragma unroll
    for (int i = 0; i < 4; ++i) { mrow[qi][i] = -1e30f; lrow[qi][i] = 0.f; }
#pragma unroll
  for (int qi = 0; qi < 2; ++qi)
#pragma unroll
    for (int df = 0; df < 4; ++df) acco[qi][df] = zf;

  for (int t0 = 0; t0 < 2048; t0 += 64) {
#pragma unroll
    for (int j = 0; j < 2; ++j) {
      const int idx = w * 2 + j, kk = idx >> 2, mb = idx & 3;
      gl_lds16(Kb + (size_t)(t0 + mb * 16 + sr) * 64 + kk * 32 + sg * 8, &Ks[idx * 1024]);
      gl_lds16(Vb + (size_t)(mb * 16 + sr) * 2048 + t0 + kk * 32 + sg * 8, &Vs[idx * 1024]);
    }
    __syncthreads();

    // S = Q K^T  (scale folded into Q)
    f32x4 s[2][4];
#pragma unroll
    for (int qi = 0; qi < 2; ++qi)
#pragma unroll
      for (int nf = 0; nf < 4; ++nf) s[qi][nf] = zf;
#pragma unroll
    for (int kk = 0; kk < 2; ++kk) {
      bf16x8 qf[2], kf[4];
      qf[0] = *(const bf16x8*)&Qs[(kk * 8 + qb0) * 1024 + c * 64 + gg * 16];
      qf[1] = *(const bf16x8*)&Qs[(kk * 8 + qb0 + 1) * 1024 + c * 64 + gg * 16];
#pragma unroll
      for (int nf = 0; nf < 4; ++nf)
        kf[nf] = *(const bf16x8*)&Ks[(kk * 4 + nf) * 1024 + c * 64 + gg * 16];
#pragma unroll
      for (int qi = 0; qi < 2; ++qi)
#pragma unroll
        for (int nf = 0; nf < 4; ++nf)
          s[qi][nf] = __builtin_amdgcn_mfma_f32_16x16x32_bf16(
              qf[qi], kf[nf], s[qi][nf], 0, 0, 0);
    }

    // online softmax (+ dense edge bias), write P to per-wave LDS
#pragma unroll
    for (int qi = 0; qi < 2; ++qi) {
#pragma unroll
      for (int i = 0; i < 4; ++i) {
        const int qg = q0 + w * 32 + qi * 16 + gg * 4 + i;
        const float* bp = Bias + (size_t)qg * 2048 + t0 + c;
        float v0 = s[qi][0][i] + bp[0];
        float v1 = s[qi][1][i] + bp[16];
        float v2 = s[qi][2][i] + bp[32];
        float v3 = s[qi][3][i] + bp[48];
        float tm = fmaxf(fmaxf(v0, v1), fmaxf(v2, v3));
#pragma unroll
        for (int d2 = 1; d2 < 16; d2 <<= 1) tm = fmaxf(tm, __shfl_xor(tm, d2));
        const float mold = mrow[qi][i];
        const float mnew = fmaxf(mold, tm);
        const float alpha = __expf(mold - mnew);
        mrow[qi][i] = mnew;
        const float p0 = __expf(v0 - mnew), p1 = __expf(v1 - mnew);
        const float p2 = __expf(v2 - mnew), p3 = __expf(v3 - mnew);
        float ps = p0 + p1 + p2 + p3;
#pragma unroll
        for (int d2 = 1; d2 < 16; d2 <<= 1) ps += __shfl_xor(ps, d2);
        lrow[qi][i] = lrow[qi][i] * alpha + ps;
#pragma unroll
        for (int df = 0; df < 4; ++df) acco[qi][df][i] *= alpha;
        const int rloc = gg * 4 + i;
        const ushort pb[4] = {f2bf(p0), f2bf(p1), f2bf(p2), f2bf(p3)};
#pragma unroll
        for (int nf = 0; nf < 4; ++nf) {
          const int kl = nf * 16 + c;
          const int kkp = kl >> 5, gp = (kl >> 3) & 3, pos = kl & 7;
          *(ushort*)&Ps[w * 4096 + ((kkp * 2 + qi) * 64 + rloc * 4 + gp) * 16 + pos * 2] = pb[nf];
        }
      }
    }
    __syncthreads();

    // O += P * V
#pragma unroll
    for (int kk = 0; kk < 2; ++kk) {
      bf16x8 pa[2], vb2[4];
      pa[0] = *(const bf16x8*)&Ps[w * 4096 + (kk * 2 + 0) * 1024 + c * 64 + gg * 16];
      pa[1] = *(const bf16x8*)&Ps[w * 4096 + (kk * 2 + 1) * 1024 + c * 64 + gg * 16];
#pragma unroll
      for (int df = 0; df < 4; ++df)
        vb2[df] = *(const bf16x8*)&Vs[(kk * 4 + df) * 1024 + c * 64 + gg * 16];
#pragma unroll
      for (int qi = 0; qi < 2; ++qi)
#pragma unroll
        for (int df = 0; df < 4; ++df)
          acco[qi][df] = __builtin_amdgcn_mfma_f32_16x16x32_bf16(
              pa[qi], vb2[df], acco[qi][df], 0, 0, 0);
    }
    __syncthreads();
  }

#pragma unroll
  for (int qi = 0; qi < 2; ++qi) {
#pragma unroll
    for (int i = 0; i < 4; ++i) {
      const float inv = 1.f / lrow[qi][i];
      const int qg = q0 + w * 32 + qi * 16 + gg * 4 + i;
#pragma unroll
      for (int df = 0; df < 4; ++df)
        Out[(size_t)(bI * 2048 + qg) * 1024 + h * 64 + df * 16 + c] =
            f2bf(acco[qi][df][i] * inv);
    }
  }
}

// ---------------- launch ----------------
extern "C" void kernel_launch(void* const* d_in, const int* in_sizes, int n_in,
                              void* d_out, int out_size, void* d_ws, size_t ws_size,
                              hipStream_t stream) {
  (void)n_in; (void)out_size; (void)ws_size;
  const float* x   = (const float*)d_in[0];
  const float* Wq  = (const float*)d_in[1];
  const float* bq  = (const float*)d_in[2];
  const float* Wk  = (const float*)d_in[3];
  const float* bk  = (const float*)d_in[4];
  const float* Wv  = (const float*)d_in[5];
  const float* bv  = (const float*)d_in[6];
  const float* Wo  = (const float*)d_in[7];
  const float* bo  = (const float*)d_in[8];
  const float* emb = (const float*)d_in[9];
  const float* tw  = (const float*)d_in[10];
  const int* esrc  = (const int*)d_in[11];
  const int* edst  = (const int*)d_in[12];
  const int* etyp  = (const int*)d_in[13];
  const int E = in_sizes[11];

  char* ws = (char*)d_ws;
  const size_t MB = 1u << 20;
  ushort* Wtq = (ushort*)(ws + 0 * MB);
  ushort* Wtk = (ushort*)(ws + 2 * MB);
  ushort* Wtv = (ushort*)(ws + 4 * MB);
  ushort* Wto = (ushort*)(ws + 6 * MB);
  ushort* Wt3 = Wtq;  // contiguous [3072][1024]
  ushort* Qb  = (ushort*)(ws + 8 * MB);
  ushort* Kb  = (ushort*)(ws + 16 * MB);
  ushort* Vtb = (ushort*)(ws + 24 * MB);
  ushort* Ab  = (ushort*)(ws + 32 * MB);
  float*  Bias = (float*)(ws + 40 * MB);
  float*  b3   = (float*)(ws + 56 * MB);
  ushort* xbf = (ushort*)d_out;  // scratch in d_out, dead before final GEMM

  cvtx_kernel<<<4096, 256, 0, stream>>>(x, xbf);
  dim3 tg(32, 32);
  tcvt_kernel<<<tg, 256, 0, stream>>>(Wq, Wtq);
  tcvt_kernel<<<tg, 256, 0, stream>>>(Wk, Wtk);
  tcvt_kernel<<<tg, 256, 0, stream>>>(Wv, Wtv);
  tcvt_kernel<<<tg, 256, 0, stream>>>(Wo, Wto);
  bias3_kernel<<<3, 256, 0, stream>>>(emb, tw, b3);
  (void)hipMemsetAsync(Bias, 0, (size_t)2048 * 2048 * 4, stream);
  scatter_kernel<<<(E + 255) / 256, 256, 0, stream>>>(esrc, edst, etyp, b3, Bias, E);

  dim3 gqkv(24, 32);
  gemm_qkv_kernel<<<gqkv, 256, 0, stream>>>(xbf, Wt3, bq, bk, bv, Qb, Kb, Vtb);
  dim3 ga(16, 32);
  attn_kernel<<<ga, 256, 0, stream>>>(Qb, Kb, Vtb, Bias, Ab);
  dim3 go(8, 32);
  gemm_out_kernel<<<go, 256, 0, stream>>>(Ab, Wto, bo, (float*)d_out);
}

// Round 2
// 205.026 us; speedup vs baseline: 1.1750x; 1.1750x over previous
//
#include <hip/hip_runtime.h>

// GraphAttentionWithTypedEdges — MI355X bf16 MFMA implementation, round 2.
// B=2, T=2048, D=1024, H=16, hd=64, E=16384.
//
// Round-2 change: attention rewritten to the 8-warp swapped-QK^T structure
// (mfma(K,Q) -> lane-local P rows; in-register P->A-frag via cvt_pk_bf16 +
// permlane32_swap; defer-max; XOR-swizzled K/V LDS; exp(Bias) precomputed and
// multiplied into P post-exp — exact by softmax shift invariance).
//
// ws layout (bytes):
//   [0,8M)    Wt3: Wq^T,Wk^T,Wv^T,Wo^T bf16, each [1024][1024]
//   [8M,16M)  Q  bf16 [B,H,T,64] (pre-scaled by 0.125)
//   [16M,24M) K  bf16 [B,H,T,64]
//   [24M,32M) Vt bf16 [B,H,64,T]
//   [32M,40M) attn out bf16 [B,T,H*64]
//   [40M,56M) Bias fp32 [2048][2048] (scatter-add, then exp'd in place)
//   [56M,+16) bias3 fp32[3]
// d_out first 8 MB doubles as x_bf16 scratch (dead before final GEMM writes).

typedef __attribute__((ext_vector_type(4))) float f32x4;
typedef __attribute__((ext_vector_type(16))) float f32x16;
typedef __bf16 bf16x8 __attribute__((ext_vector_type(8)));

#define DEV static __device__ __forceinline__

DEV ushort f2bf(float f) {
  unsigned u = __float_as_uint(f);
  unsigned r = u + 0x7fffu + ((u >> 16) & 1u);
  return (ushort)(r >> 16);
}

DEV void gl_lds16(const void* g, void* l) {
  __builtin_amdgcn_global_load_lds(
      (const __attribute__((address_space(1))) void*)g,
      (__attribute__((address_space(3))) void*)l, 16, 0, 0);
}

DEV f32x16 mfma32(bf16x8 a, bf16x8 b, f32x16 c) {
  return __builtin_amdgcn_mfma_f32_32x32x16_bf16(a, b, c, 0, 0, 0);
}

DEV unsigned cvtpk(float a, float b) {
  unsigned r;
  asm("v_cvt_pk_bf16_f32 %0, %1, %2" : "=v"(r) : "v"(a), "v"(b));
  return r;
}

// ---------------- conversions ----------------
__global__ __launch_bounds__(256) void cvtx_kernel(const float* __restrict__ X,
                                                   ushort* __restrict__ Y) {
  int i = blockIdx.x * 256 + threadIdx.x;
  float4 v = ((const float4*)X)[i];
  ushort4 o;
  o.x = f2bf(v.x); o.y = f2bf(v.y); o.z = f2bf(v.z); o.w = f2bf(v.w);
  ((ushort4*)Y)[i] = o;
}

// W [1024][1024] fp32 -> Wt [1024][1024] bf16 with Wt[n][k] = W[k][n]
__global__ __launch_bounds__(256) void tcvt_kernel(const float* __restrict__ W,
                                                   ushort* __restrict__ Wt) {
  __shared__ float tile[32][33];
  int bx = blockIdx.x * 32, by = blockIdx.y * 32;
  int tx = threadIdx.x & 31, ty = threadIdx.x >> 5;
#pragma unroll
  for (int i = 0; i < 32; i += 8)
    tile[ty + i][tx] = W[(size_t)(by + ty + i) * 1024 + bx + tx];
  __syncthreads();
#pragma unroll
  for (int i = 0; i < 32; i += 8)
    Wt[(size_t)(bx + ty + i) * 1024 + by + tx] = f2bf(tile[tx][ty + i]);
}

// ---------------- edge bias ----------------
__global__ __launch_bounds__(256) void bias3_kernel(const float* __restrict__ emb,
                                                    const float* __restrict__ tw,
                                                    float* __restrict__ b3) {
  __shared__ float red[256];
  const int t = blockIdx.x;
  float p = 0.f;
  for (int d = threadIdx.x; d < 1024; d += 256) p += emb[t * 1024 + d] * tw[d];
  red[threadIdx.x] = p;
  __syncthreads();
  for (int s = 128; s > 0; s >>= 1) {
    if (threadIdx.x < s) red[threadIdx.x] += red[threadIdx.x + s];
    __syncthreads();
  }
  if (threadIdx.x == 0) b3[t] = red[0];
}

__global__ __launch_bounds__(256) void scatter_kernel(
    const int* __restrict__ src, const int* __restrict__ dst,
    const int* __restrict__ typ, const float* __restrict__ b3,
    float* __restrict__ Bias, int E) {
  int e = blockIdx.x * 256 + threadIdx.x;
  if (e < E) atomicAdd(&Bias[(size_t)src[e] * 2048 + dst[e]], b3[typ[e]]);
}

// In-place exp of the dense bias matrix: ExpB = exp(Bias).
__global__ __launch_bounds__(256) void expb_kernel(float* __restrict__ B) {
  int i = blockIdx.x * 256 + threadIdx.x;
  f32x4 v = ((f32x4*)B)[i];
#pragma unroll
  for (int j = 0; j < 4; ++j) v[j] = __expf(v[j]);
  ((f32x4*)B)[i] = v;
}

// ---------------- GEMMs (unchanged from round 1) ----------------
__global__ __launch_bounds__(256) void gemm_qkv_kernel(
    const ushort* __restrict__ A, const ushort* __restrict__ Bt3,
    const float* __restrict__ bq, const float* __restrict__ bk,
    const float* __restrict__ bv, ushort* __restrict__ Qo,
    ushort* __restrict__ Ko, ushort* __restrict__ Vto) {
  __shared__ alignas(16) char Als[16384];
  __shared__ alignas(16) char Bls[16384];
  const int tid = threadIdx.x, w = tid >> 6, l = tid & 63;
  const int m0 = blockIdx.y * 128, n0 = blockIdx.x * 128;
  const int sr = l >> 2, sg = l & 3;
  const int c = l & 15, gg = l >> 4;
  const int wr = (w >> 1) * 64, wc = (w & 1) * 64;

  f32x4 acc[4][4];
  const f32x4 zf = {0.f, 0.f, 0.f, 0.f};
#pragma unroll
  for (int a2 = 0; a2 < 4; ++a2)
#pragma unroll
    for (int b2 = 0; b2 < 4; ++b2) acc[a2][b2] = zf;

  for (int k0 = 0; k0 < 1024; k0 += 64) {
#pragma unroll
    for (int j = 0; j < 4; ++j) {
      const int idx = w * 4 + j, kk = idx >> 3, mb = idx & 7;
      gl_lds16(A + (size_t)(m0 + mb * 16 + sr) * 1024 + k0 + kk * 32 + sg * 8,
               &Als[idx * 1024]);
      gl_lds16(Bt3 + (size_t)(n0 + mb * 16 + sr) * 1024 + k0 + kk * 32 + sg * 8,
               &Bls[idx * 1024]);
    }
    __syncthreads();
#pragma unroll
    for (int kk = 0; kk < 2; ++kk) {
      bf16x8 af[4], bfr[4];
#pragma unroll
      for (int f = 0; f < 4; ++f) {
        af[f]  = *(const bf16x8*)&Als[(kk * 8 + (wr >> 4) + f) * 1024 + c * 64 + gg * 16];
        bfr[f] = *(const bf16x8*)&Bls[(kk * 8 + (wc >> 4) + f) * 1024 + c * 64 + gg * 16];
      }
#pragma unroll
      for (int mf = 0; mf < 4; ++mf)
#pragma unroll
        for (int nf = 0; nf < 4; ++nf)
          acc[mf][nf] = __builtin_amdgcn_mfma_f32_16x16x32_bf16(
              af[mf], bfr[nf], acc[mf][nf], 0, 0, 0);
    }
    __syncthreads();
  }

  const int which = n0 >> 10;
  const float scale = (which == 0) ? 0.125f : 1.0f;
  const float* bias = (which == 0) ? bq : (which == 1) ? bk : bv;
  ushort* outp = (which == 0) ? Qo : (which == 1) ? Ko : Vto;
#pragma unroll
  for (int mf = 0; mf < 4; ++mf) {
#pragma unroll
    for (int nf = 0; nf < 4; ++nf) {
      const int coln = (n0 & 1023) + wc + nf * 16 + c;
      const float bvv = bias[coln];
      const int h = coln >> 6, d = coln & 63;
#pragma unroll
      for (int i = 0; i < 4; ++i) {
        const int row = m0 + wr + mf * 16 + gg * 4 + i;
        const int b = row >> 11, t = row & 2047;
        const float v = (acc[mf][nf][i] + bvv) * scale;
        if (which < 2)
          outp[((size_t)(b * 16 + h) * 2048 + t) * 64 + d] = f2bf(v);
        else
          outp[((size_t)(b * 16 + h) * 64 + d) * 2048 + t] = f2bf(v);
      }
    }
  }
}

__global__ __launch_bounds__(256) void gemm_out_kernel(
    const ushort* __restrict__ A, const ushort* __restrict__ Bt,
    const float* __restrict__ bias, float* __restrict__ outp) {
  __shared__ alignas(16) char Als[16384];
  __shared__ alignas(16) char Bls[16384];
  const int tid = threadIdx.x, w = tid >> 6, l = tid & 63;
  const int m0 = blockIdx.y * 128, n0 = blockIdx.x * 128;
  const int sr = l >> 2, sg = l & 3;
  const int c = l & 15, gg = l >> 4;
  const int wr = (w >> 1) * 64, wc = (w & 1) * 64;

  f32x4 acc[4][4];
  const f32x4 zf = {0.f, 0.f, 0.f, 0.f};
#pragma unroll
  for (int a2 = 0; a2 < 4; ++a2)
#pragma unroll
    for (int b2 = 0; b2 < 4; ++b2) acc[a2][b2] = zf;

  for (int k0 = 0; k0 < 1024; k0 += 64) {
#pragma unroll
    for (int j = 0; j < 4; ++j) {
      const int idx = w * 4 + j, kk = idx >> 3, mb = idx & 7;
      gl_lds16(A + (size_t)(m0 + mb * 16 + sr) * 1024 + k0 + kk * 32 + sg * 8,
               &Als[idx * 1024]);
      gl_lds16(Bt + (size_t)(n0 + mb * 16 + sr) * 1024 + k0 + kk * 32 + sg * 8,
               &Bls[idx * 1024]);
    }
    __syncthreads();
#pragma unroll
    for (int kk = 0; kk < 2; ++kk) {
      bf16x8 af[4], bfr[4];
#pragma unroll
      for (int f = 0; f < 4; ++f) {
        af[f]  = *(const bf16x8*)&Als[(kk * 8 + (wr >> 4) + f) * 1024 + c * 64 + gg * 16];
        bfr[f] = *(const bf16x8*)&Bls[(kk * 8 + (wc >> 4) + f) * 1024 + c * 64 + gg * 16];
      }
#pragma unroll
      for (int mf = 0; mf < 4; ++mf)
#pragma unroll
        for (int nf = 0; nf < 4; ++nf)
          acc[mf][nf] = __builtin_amdgcn_mfma_f32_16x16x32_bf16(
              af[mf], bfr[nf], acc[mf][nf], 0, 0, 0);
    }
    __syncthreads();
  }

#pragma unroll
  for (int mf = 0; mf < 4; ++mf) {
#pragma unroll
    for (int nf = 0; nf < 4; ++nf) {
      const int col = n0 + wc + nf * 16 + c;
      const float bvv = bias[col];
#pragma unroll
      for (int i = 0; i < 4; ++i) {
        const int row = m0 + wr + mf * 16 + gg * 4 + i;
        outp[(size_t)row * 1024 + col] = acc[mf][nf][i] + bvv;
      }
    }
  }
}

// ---------------- flash attention v2 (swapped QK^T, 32x32x16) ----------------
// grid (32 bh, 16 qtiles), 256 threads = 4 waves; wave w owns 32 q rows.
// S^T = mfma(K, Q): C col = lane&31 = q, row = (reg&3)+8*(reg>>2)+4*(lane>>5) = k.
// P -> PV A-frag in-register via cvt_pk_bf16 + v_permlane32_swap_b32.
// K/V LDS tiles [64][128B] XOR-swizzled (byte ^= (row&7)<<4) via pre-swizzled
// global source addresses (global_load_lds dest stays linear).
__global__ __launch_bounds__(256) void attn2_kernel(
    const ushort* __restrict__ Q, const ushort* __restrict__ K,
    const ushort* __restrict__ Vt, const float* __restrict__ ExpB,
    ushort* __restrict__ Out) {
  __shared__ alignas(16) char Ks[2][8192];
  __shared__ alignas(16) char Vs[2][8192];
  __shared__ float alds[4][32];
  const int tid = threadIdx.x, w = tid >> 6, l = tid & 63;
  const int c = l & 31, hi = l >> 5;
  const int bh = blockIdx.x, q0 = blockIdx.y * 128;
  const int bI = bh >> 4, h = bh & 15;
  const int qbase = q0 + w * 32;
  const char* Kg = (const char*)(K + (size_t)bh * 2048 * 64);
  const char* Vg = (const char*)(Vt + (size_t)bh * 64 * 2048);

  // Q fragments (B-operand of mfma(K,Q)): Qf[ds][j] = Q[qbase+c][ds*16+hi*8+j]
  const ushort* Qp = Q + ((size_t)bh * 2048 + qbase + c) * 64 + hi * 8;
  bf16x8 Qf[4];
#pragma unroll
  for (int ds = 0; ds < 4; ++ds) Qf[ds] = *(const bf16x8*)(Qp + ds * 16);

  // staging geometry (chunk i = j*256 + w*64 + l, 16B each)
  const int srb = w * 8 + (l >> 3);               // row within 32-row half
  const int scol = ((l & 7) << 4) ^ ((l >> 3) << 4);  // pre-swizzled src col
  const int cx = (c & 7) << 4;                    // read-side XOR

  f32x16 oacc0 = {0,0,0,0,0,0,0,0,0,0,0,0,0,0,0,0};
  f32x16 oacc1 = {0,0,0,0,0,0,0,0,0,0,0,0,0,0,0,0};
  float m_run = -3.0e38f, l_run = 0.f;

  auto STAGE = [&](int buf, int t0) {
#pragma unroll
    for (int j = 0; j < 2; ++j) {
      const int r = j * 32 + srb;
      gl_lds16(Kg + (size_t)(t0 + r) * 128 + scol, &Ks[buf][j * 4096 + w * 1024]);
      gl_lds16(Vg + (size_t)r * 4096 + (size_t)t0 * 2 + scol, &Vs[buf][j * 4096 + w * 1024]);
    }
  };

  STAGE(0, 0);
  for (int t = 0; t < 32; ++t) {
    const int cur = t & 1;
    __syncthreads();  // drains vmcnt -> stage(t) visible; prior reads done
    if (t < 31) STAGE(cur ^ 1, (t + 1) * 64);
    const char* KsC = Ks[cur];
    const char* VsC = Vs[cur];

    // ---- S^T = K * Q over 64 keys (two 32-key MFMAs per 16-d slice) ----
    f32x16 s0 = {0,0,0,0,0,0,0,0,0,0,0,0,0,0,0,0};
    f32x16 s1 = {0,0,0,0,0,0,0,0,0,0,0,0,0,0,0,0};
#pragma unroll
    for (int ds = 0; ds < 4; ++ds) {
      const int col = (ds * 32 + hi * 16) ^ cx;
      bf16x8 k0 = *(const bf16x8*)(KsC + c * 128 + col);
      bf16x8 k1 = *(const bf16x8*)(KsC + (32 + c) * 128 + col);
      s0 = mfma32(k0, Qf[ds], s0);
      s1 = mfma32(k1, Qf[ds], s1);
    }

    // ---- exp(bias) loads: eb[kt*4+g][e] pairs with s_kt[4g+e] ----
    const float* ebp = ExpB + (size_t)(qbase + c) * 2048 + t * 64 + hi * 4;
    f32x4 eb[8];
#pragma unroll
    for (int g = 0; g < 8; ++g) eb[g] = *(const f32x4*)(ebp + 8 * g);

    // ---- row max (lane-local tree + cross-half) ----
    f32x16 mx;
#pragma unroll
    for (int r = 0; r < 16; ++r) mx[r] = fmaxf(s0[r], s1[r]);
#pragma unroll
    for (int off = 8; off; off >>= 1)
#pragma unroll
      for (int r = 0; r < off; ++r) mx[r] = fmaxf(mx[r], mx[r + off]);
    const float mt = fmaxf(mx[0], __shfl_xor(mx[0], 32));

    // ---- defer-max rescale (rare) ----
    if (__any(mt > m_run + 8.0f)) {
      const float mnew = fmaxf(m_run, mt);
      const float alpha = __expf(m_run - mnew);
      m_run = mnew;
      l_run *= alpha;
      alds[w][c] = alpha;  // lanes hi=0/1 write identical values
      const float* ap = &alds[w][hi * 4];
      f32x4 av[4];
#pragma unroll
      for (int g = 0; g < 4; ++g) av[g] = *(const f32x4*)(ap + 8 * g);
#pragma unroll
      for (int r = 0; r < 16; ++r) {
        const float a = av[r >> 2][r & 3];
        oacc0[r] *= a;
        oacc1[r] *= a;
      }
    }

    // ---- p = exp(s - m) * eb; row sum ----
    f32x16 ps;
#pragma unroll
    for (int r = 0; r < 16; ++r) {
      const int g = r >> 2, e = r & 3;
      const float p0 = __expf(s0[r] - m_run) * eb[g][e];
      const float p1 = __expf(s1[r] - m_run) * eb[4 + g][e];
      s0[r] = p0; s1[r] = p1; ps[r] = p0 + p1;
    }
#pragma unroll
    for (int off = 8; off; off >>= 1)
#pragma unroll
      for (int r = 0; r < off; ++r) ps[r] += ps[r + off];
    l_run += ps[0] + __shfl_xor(ps[0], 32);

    // ---- P -> A-frags: cvt_pk pairs + permlane32_swap cross-half ----
    bf16x8 paf[2][2];
#pragma unroll
    for (int kt = 0; kt < 2; ++kt) {
      const f32x16& sv = kt ? s1 : s0;
#pragma unroll
      for (int sl = 0; sl < 2; ++sl) {
        const int rb = sl * 8;
        unsigned u0 = cvtpk(sv[rb + 0], sv[rb + 1]);
        unsigned u1 = cvtpk(sv[rb + 2], sv[rb + 3]);
        unsigned u2 = cvtpk(sv[rb + 4], sv[rb + 5]);
        unsigned u3 = cvtpk(sv[rb + 6], sv[rb + 7]);
        asm("v_permlane32_swap_b32 %0, %1" : "+v"(u0), "+v"(u2));
        asm("v_permlane32_swap_b32 %0, %1" : "+v"(u1), "+v"(u3));
        uint4 uu = {u0, u1, u2, u3};
        paf[kt][sl] = *(bf16x8*)&uu;
      }
    }

    // ---- O += P * V ----
#pragma unroll
    for (int kt = 0; kt < 2; ++kt)
#pragma unroll
      for (int sl = 0; sl < 2; ++sl) {
        const int ks = kt * 2 + sl;
        const int col = (ks * 32 + hi * 16) ^ cx;
        bf16x8 v0 = *(const bf16x8*)(VsC + c * 128 + col);
        bf16x8 v1 = *(const bf16x8*)(VsC + (32 + c) * 128 + col);
        oacc0 = mfma32(paf[kt][sl], v0, oacc0);
        oacc1 = mfma32(paf[kt][sl], v1, oacc1);
      }
  }

  // ---- epilogue: normalize (broadcast 1/l via LDS) and store ----
  const float linv = 1.0f / l_run;
  alds[w][c] = linv;
  const float* lp = &alds[w][hi * 4];
  f32x4 lv[4];
#pragma unroll
  for (int g = 0; g < 4; ++g) lv[g] = *(const f32x4*)(lp + 8 * g);
  ushort* Ob = Out + (size_t)(bI * 2048 + qbase) * 1024 + h * 64;
#pragma unroll
  for (int r = 0; r < 16; ++r) {
    const int qr = (r & 3) + 8 * (r >> 2) + 4 * hi;
    const float sc = lv[r >> 2][r & 3];
    Ob[(size_t)qr * 1024 + c] = f2bf(oacc0[r] * sc);
    Ob[(size_t)qr * 1024 + 32 + c] = f2bf(oacc1[r] * sc);
  }
}

// ---------------- launch ----------------
extern "C" void kernel_launch(void* const* d_in, const int* in_sizes, int n_in,
                              void* d_out, int out_size, void* d_ws, size_t ws_size,
                              hipStream_t stream) {
  (void)n_in; (void)out_size; (void)ws_size;
  const float* x   = (const float*)d_in[0];
  const float* Wq  = (const float*)d_in[1];
  const float* bq  = (const float*)d_in[2];
  const float* Wk  = (const float*)d_in[3];
  const float* bk  = (const float*)d_in[4];
  const float* Wv  = (const float*)d_in[5];
  const float* bv  = (const float*)d_in[6];
  const float* Wo  = (const float*)d_in[7];
  const float* bo  = (const float*)d_in[8];
  const float* emb = (const float*)d_in[9];
  const float* tw  = (const float*)d_in[10];
  const int* esrc  = (const int*)d_in[11];
  const int* edst  = (const int*)d_in[12];
  const int* etyp  = (const int*)d_in[13];
  const int E = in_sizes[11];

  char* ws = (char*)d_ws;
  const size_t MB = 1u << 20;
  ushort* Wtq = (ushort*)(ws + 0 * MB);
  ushort* Wtk = (ushort*)(ws + 2 * MB);
  ushort* Wtv = (ushort*)(ws + 4 * MB);
  ushort* Wto = (ushort*)(ws + 6 * MB);
  ushort* Wt3 = Wtq;  // contiguous [3072][1024]
  ushort* Qb  = (ushort*)(ws + 8 * MB);
  ushort* Kb  = (ushort*)(ws + 16 * MB);
  ushort* Vtb = (ushort*)(ws + 24 * MB);
  ushort* Ab  = (ushort*)(ws + 32 * MB);
  float*  Bias = (float*)(ws + 40 * MB);
  float*  b3   = (float*)(ws + 56 * MB);
  ushort* xbf = (ushort*)d_out;  // scratch in d_out, dead before final GEMM

  cvtx_kernel<<<4096, 256, 0, stream>>>(x, xbf);
  dim3 tg(32, 32);
  tcvt_kernel<<<tg, 256, 0, stream>>>(Wq, Wtq);
  tcvt_kernel<<<tg, 256, 0, stream>>>(Wk, Wtk);
  tcvt_kernel<<<tg, 256, 0, stream>>>(Wv, Wtv);
  tcvt_kernel<<<tg, 256, 0, stream>>>(Wo, Wto);
  bias3_kernel<<<3, 256, 0, stream>>>(emb, tw, b3);
  (void)hipMemsetAsync(Bias, 0, (size_t)2048 * 2048 * 4, stream);
  scatter_kernel<<<(E + 255) / 256, 256, 0, stream>>>(esrc, edst, etyp, b3, Bias, E);
  expb_kernel<<<4096, 256, 0, stream>>>(Bias);

  dim3 gqkv(24, 32);
  gemm_qkv_kernel<<<gqkv, 256, 0, stream>>>(xbf, Wt3, bq, bk, bv, Qb, Kb, Vtb);
  dim3 ga(32, 16);
  attn2_kernel<<<ga, 256, 0, stream>>>(Qb, Kb, Vtb, Bias, Ab);
  dim3 go(8, 32);
  gemm_out_kernel<<<go, 256, 0, stream>>>(Ab, Wto, bo, (float*)d_out);
}